// Round 9
// baseline (239.071 us; speedup 1.0000x reference)
//
#include <hip/hip_runtime.h>

typedef unsigned short u16;
typedef unsigned int u32;
typedef __bf16 bf16x8 __attribute__((ext_vector_type(8)));
typedef float f32x4 __attribute__((ext_vector_type(4)));
typedef u16 u16x8 __attribute__((ext_vector_type(8)));
typedef u16 u16x4 __attribute__((ext_vector_type(4)));

// B=8, N=512, D=512, H=8, DH=64, E=32768, BIAS_DIM=8
// MEASUREMENT ROUND 2: exact R4 chain with prologue x6 and out_gemm x6
// (both idempotent; all prologues precede qkv so bias re-zeroing is safe).
// dur = 133.5 + 5*(prologue + out).  R8 gave attn = 15.6us (warm marginal).
// This pins the remaining ~118us among {prologue, qkv, out, cold gaps}.

__device__ __forceinline__ u16 f2b(float f) {
  union { float f; u32 i; } v; v.f = f;
  u32 r = v.i + 0x7fffu + ((v.i >> 16) & 1u);
  return (u16)(r >> 16);
}

#define GLL16(gp, lp)                                                      \
  __builtin_amdgcn_global_load_lds(                                       \
      (const __attribute__((address_space(1))) u32*)(gp),                 \
      (__attribute__((address_space(3))) u32*)(lp), 16, 0, 0)

// DMA-stage a 64x64 bf16 tile (row stride 512) into linear LDS; source
// granule pre-swizzled so LDS(r,g) holds global (r, g^(r&7)).
__device__ __forceinline__ void stage64(const u16* g, u16* l, int wave, int lane) {
  int rsub = lane >> 3;
  int gs = (((lane & 7) ^ rsub) << 3);
  #pragma unroll
  for (int c = 0; c < 2; c++) {
    int ch = wave * 2 + c;
    GLL16(g + (size_t)(ch * 8 + rsub) * 512 + gs, l + ch * 512);
  }
}
__device__ __forceinline__ void stage128(const u16* g, u16* l, int wave, int lane) {
  int rsub = lane >> 3;
  int gs = (((lane & 7) ^ rsub) << 3);
  #pragma unroll
  for (int c = 0; c < 4; c++) {
    int ch = wave * 4 + c;
    GLL16(g + (size_t)(ch * 8 + rsub) * 512 + gs, l + ch * 512);
  }
}
// Swizzled read/write offset (elements) into a linear [rows][64] tile.
__device__ __forceinline__ int swz(int row, int g) {
  return row * 64 + ((g ^ (row & 7)) << 3);
}

// ---------- prologue: cvt states/key | transpose 4 weights | zero bias ----------
__global__ __launch_bounds__(256) void prologue(
    const float* __restrict__ states, const float* __restrict__ key_states,
    const float* __restrict__ Wq, const float* __restrict__ Wk,
    const float* __restrict__ Wv, const float* __restrict__ Wo,
    u16* __restrict__ sb, u16* __restrict__ kbin, u16* __restrict__ wbase,
    float* __restrict__ bias_mat) {
  __shared__ u16 t[32][33];
  int bid = blockIdx.x;
  int tid = threadIdx.x;
  if (bid < 2048) {
    const float* src = (bid >= 1024) ? key_states : states;
    u16* dst = (bid >= 1024) ? kbin : sb;
    int gid = (bid & 1023) * 256 + tid;
    const float4* sp = (const float4*)src + (size_t)gid * 2;
    float4 x0 = sp[0], x1 = sp[1];
    u16x8 p;
    p[0] = f2b(x0.x); p[1] = f2b(x0.y); p[2] = f2b(x0.z); p[3] = f2b(x0.w);
    p[4] = f2b(x1.x); p[5] = f2b(x1.y); p[6] = f2b(x1.z); p[7] = f2b(x1.w);
    *(u16x8*)(dst + (size_t)gid * 8) = p;
  } else if (bid < 3072) {
    int tt = bid - 2048;
    int z = tt >> 8, rem = tt & 255;
    int bx = rem & 15, by = rem >> 4;
    const float* src; float sc = 1.f;
    if (z == 0)      { src = Wq; sc = 0.125f; }
    else if (z == 1) { src = Wk; }
    else if (z == 2) { src = Wv; }
    else             { src = Wo; }
    u16* dst = wbase + (size_t)z * 262144;
    int tx = tid & 31, ty = tid >> 5;
    int c0 = bx * 32, r0 = by * 32;
    #pragma unroll
    for (int i = ty; i < 32; i += 8) t[i][tx] = f2b(src[(r0 + i) * 512 + c0 + tx] * sc);
    __syncthreads();
    #pragma unroll
    for (int i = ty; i < 32; i += 8) dst[(c0 + i) * 512 + r0 + tx] = t[tx][i];
  } else {
    int i = (bid - 3072) * 256 + tid;
    float4 z4 = {0.f, 0.f, 0.f, 0.f};
    ((float4*)bias_mat)[i] = z4;
  }
}

// ---------- fused QKV GEMM + edge-bias scatter; grid (64,12)=768 ----------
__global__ __launch_bounds__(256) void qkv_gemm(const u16* __restrict__ sb,
                                                const u16* __restrict__ kbin,
                                                const u16* __restrict__ wT,
                                                const int* __restrict__ ab,
                                                const float* __restrict__ be,
                                                const float* __restrict__ bsc,
                                                float* __restrict__ bias_m,
                                                u16* __restrict__ qb,
                                                u16* __restrict__ kbo,
                                                u16* __restrict__ vtb,
                                                float* __restrict__ summed,
                                                int n_edges) {
  __shared__ alignas(16) u16 As[2][64 * 64];
  __shared__ alignas(16) u16 Bs[2][128 * 64];
  __shared__ float ssum[4][64];
  __shared__ float tvs[8];
  int tid = threadIdx.x;
  int lane = tid & 63, wave = tid >> 6;
  int quad = lane >> 4, ln = lane & 15;
  int fb = blockIdx.y * 64 + blockIdx.x;

  if (tid < 8) {
    const float4* bev = (const float4*)(be + tid * 64);
    const float4* bscv = (const float4*)bsc;
    float s = 0.f;
    #pragma unroll
    for (int a4 = 0; a4 < 16; a4++) {
      float4 x = bev[a4], y = bscv[a4];
      s += x.x * y.x + x.y * y.y + x.z * y.z + x.w * y.w;
    }
    tvs[tid] = s * 0.125f;
  }
  __syncthreads();
  for (int e = fb * 256 + tid; e < n_edges; e += 768 * 256) {
    int et = ab[e * 4 + 0];
    int b  = ab[e * 4 + 1];
    int qi = ab[e * 4 + 2];
    int ki = ab[e * 4 + 3];
    atomicAdd(&bias_m[((size_t)b * 512 + qi) * 512 + ki], tvs[et]);
  }

  int row0 = blockIdx.x * 64;
  int col0 = blockIdx.y * 128;
  const u16* A = (col0 < 512) ? sb : kbin;
  const u16* Ab = A + (size_t)row0 * 512;
  const u16* Bb = wT + (size_t)col0 * 512;

  f32x4 acc[4][2];
  #pragma unroll
  for (int i = 0; i < 4; i++)
    #pragma unroll
    for (int j = 0; j < 2; j++) acc[i][j] = (f32x4){0.f, 0.f, 0.f, 0.f};

  stage64(Ab, As[0], wave, lane);
  stage128(Bb, Bs[0], wave, lane);

  int cur = 0;
  for (int k0 = 0; k0 < 512; k0 += 64) {
    __syncthreads();
    if (k0 < 448) {
      stage64(Ab + k0 + 64, As[cur ^ 1], wave, lane);
      stage128(Bb + k0 + 64, Bs[cur ^ 1], wave, lane);
    }
    #pragma unroll
    for (int s = 0; s < 2; s++) {
      bf16x8 af[4], bfv[2];
      #pragma unroll
      for (int i = 0; i < 4; i++)
        af[i] = *(bf16x8*)&As[cur][swz(i * 16 + ln, s * 4 + quad)];
      #pragma unroll
      for (int j = 0; j < 2; j++)
        bfv[j] = *(bf16x8*)&Bs[cur][swz(wave * 32 + j * 16 + ln, s * 4 + quad)];
      #pragma unroll
      for (int i = 0; i < 4; i++)
        #pragma unroll
        for (int j = 0; j < 2; j++)
          acc[i][j] = __builtin_amdgcn_mfma_f32_16x16x32_bf16(af[i], bfv[j], acc[i][j], 0, 0, 0);
    }
    cur ^= 1;
  }

  int region = col0 >> 9;
  int nbase = col0 & 511;
  if (region <= 1) {
    u16* Cout = region ? kbo : qb;
    #pragma unroll
    for (int i = 0; i < 4; i++)
      #pragma unroll
      for (int j = 0; j < 2; j++) {
        int mb = row0 + i * 16 + quad * 4;
        int n = nbase + wave * 32 + j * 16 + ln;
        #pragma unroll
        for (int r = 0; r < 4; r++)
          Cout[(size_t)(mb + r) * 512 + n] = f2b(acc[i][j][r]);
      }
    if (region == 1) {
      #pragma unroll
      for (int i = 0; i < 4; i++)
        #pragma unroll
        for (int r = 0; r < 4; r++) {
          float v = acc[i][0][r] + acc[i][1][r];
          v += __shfl_xor(v, 1);
          v += __shfl_xor(v, 2);
          v += __shfl_xor(v, 4);
          v += __shfl_xor(v, 8);
          if (ln == 0) ssum[wave][i * 16 + quad * 4 + r] = v;
        }
      __syncthreads();
      if (tid < 128) {
        int hl = tid >> 6, row = tid & 63;
        float s = ssum[hl * 2][row] + ssum[hl * 2 + 1][row];
        int m = row0 + row;
        int b = m >> 9, t = m & 511;
        int h = (nbase >> 6) + hl;
        summed[((size_t)(b * 8 + h)) * 512 + t] = s;
      }
    }
  } else {
    #pragma unroll
    for (int i = 0; i < 4; i++)
      #pragma unroll
      for (int j = 0; j < 2; j++) {
        int mb = row0 + i * 16 + quad * 4;
        int bb = mb >> 9, t0 = mb & 511;
        int a_abs = nbase + wave * 32 + j * 16 + ln;
        int h = a_abs >> 6, a = a_abs & 63;
        u16x4 p;
        p[0] = f2b(acc[i][j][0]); p[1] = f2b(acc[i][j][1]);
        p[2] = f2b(acc[i][j][2]); p[3] = f2b(acc[i][j][3]);
        *(u16x4*)&vtb[(((size_t)bb * 8 + h) * 64 + a) * 512 + t0] = p;
      }
  }
}

// ---------- MFMA flash attention, decode-split, CU-balanced permutation ----------
__global__ __launch_bounds__(256) void attn_mfma(const u16* __restrict__ q,
                                                 const u16* __restrict__ k,
                                                 const u16* __restrict__ vt,
                                                 const float* __restrict__ bias_mat,
                                                 const float* __restrict__ summed,
                                                 u16* __restrict__ ctx,
                                                 float* __restrict__ Opart,
                                                 float* __restrict__ ml) {
  __shared__ alignas(16) u16 Qs[64 * 64];
  __shared__ alignas(16) u16 Ks[2][64 * 64];
  __shared__ alignas(16) u16 Vs[2][64 * 64];
  __shared__ alignas(16) u16 Ps[4][16 * 72];
  int tid = threadIdx.x;
  int wave = tid >> 6, lane = tid & 63;
  int quad = lane >> 4, ln = lane & 15;
  int p2 = blockIdx.x;
  int bh, u;
  {
    const int fours[6] = {3, 4, 6, 8, 10, 11};
    const int threes[2] = {2, 9};
    const int ones[2] = {0, 5};
    const int twos[2] = {1, 7};
    if (p2 < 384)      { bh = p2 & 63; u = fours[p2 >> 6]; }
    else if (p2 < 512) { int q2 = p2 - 384; bh = q2 & 63; u = threes[q2 >> 6]; }
    else if (p2 < 640) { int q2 = p2 - 512; bh = q2 & 63; u = ones[q2 >> 6]; }
    else               { int q2 = p2 - 640; bh = q2 & 63; u = twos[q2 >> 6]; }
  }
  int b = bh >> 3, h = bh & 7;
  int qt, kb0, kbe, part = 0;
  bool partial;
  if (u < 4) { qt = u; kb0 = 0; kbe = u; partial = false; }
  else {
    int v = u - 4; qt = 4 + (v >> 1); part = v & 1; partial = true;
    if (part == 0) { kb0 = 0; kbe = 3; } else { kb0 = 4; kbe = qt; }
  }
  int q0 = qt * 64;

  const u16* qb_ = q + ((size_t)(b * 512 + q0)) * 512 + h * 64;
  const u16* kb_ = k + ((size_t)(b * 512)) * 512 + h * 64;
  const u16* vb_ = vt + ((size_t)bh * 64) * 512;

  stage64(qb_, Qs, wave, lane);
  stage64(kb_ + (size_t)kb0 * 64 * 512, Ks[0], wave, lane);
  stage64(vb_ + kb0 * 64, Vs[0], wave, lane);

  float m_r[4], l_r[4];
  f32x4 o[4];
  #pragma unroll
  for (int r = 0; r < 4; r++) { m_r[r] = -3.40282347e38f; l_r[r] = 0.f; }
  #pragma unroll
  for (int nt = 0; nt < 4; nt++) o[nt] = (f32x4){0.f, 0.f, 0.f, 0.f};

  int qrow = q0 + wave * 16 + quad * 4;

  float c_skv[4], c_bias[4][4];
  #pragma unroll
  for (int nt = 0; nt < 4; nt++) {
    int t = kb0 * 64 + nt * 16 + ln;
    c_skv[nt] = summed[bh * 512 + t];
    const float* bp2 = bias_mat + ((size_t)(b * 512 + qrow)) * 512 + t;
    #pragma unroll
    for (int r = 0; r < 4; r++) c_bias[nt][r] = bp2[(size_t)r * 512];
  }

  int cur = 0;
  for (int kb = kb0; kb <= kbe; kb++) {
    __syncthreads();

    float n_skv[4], n_bias[4][4];
    if (kb < kbe) {
      stage64(kb_ + (size_t)(kb + 1) * 64 * 512, Ks[cur ^ 1], wave, lane);
      stage64(vb_ + (kb + 1) * 64, Vs[cur ^ 1], wave, lane);
      #pragma unroll
      for (int nt = 0; nt < 4; nt++) {
        int t = (kb + 1) * 64 + nt * 16 + ln;
        n_skv[nt] = summed[bh * 512 + t];
        const float* bp2 = bias_mat + ((size_t)(b * 512 + qrow)) * 512 + t;
        #pragma unroll
        for (int r = 0; r < 4; r++) n_bias[nt][r] = bp2[(size_t)r * 512];
      }
    }

    bf16x8 aq0 = *(bf16x8*)&Qs[swz(wave * 16 + ln, quad)];
    bf16x8 aq1 = *(bf16x8*)&Qs[swz(wave * 16 + ln, 4 + quad)];
    f32x4 s[4];
    #pragma unroll
    for (int nt = 0; nt < 4; nt++) {
      bf16x8 b0 = *(bf16x8*)&Ks[cur][swz(nt * 16 + ln, quad)];
      bf16x8 b1 = *(bf16x8*)&Ks[cur][swz(nt * 16 + ln, 4 + quad)];
      s[nt] = (f32x4){0.f, 0.f, 0.f, 0.f};
      s[nt] = __builtin_amdgcn_mfma_f32_16x16x32_bf16(aq0, b0, s[nt], 0, 0, 0);
      s[nt] = __builtin_amdgcn_mfma_f32_16x16x32_bf16(aq1, b1, s[nt], 0, 0, 0);
    }

    #pragma unroll
    for (int nt = 0; nt < 4; nt++) {
      int t = kb * 64 + nt * 16 + ln;
      #pragma unroll
      for (int r = 0; r < 4; r++) {
        float val = s[nt][r] + c_bias[nt][r] * c_skv[nt];
        s[nt][r] = (t <= qrow + r) ? val : -3.40282347e38f;
      }
    }

    float alpha[4];
    #pragma unroll
    for (int r = 0; r < 4; r++) {
      float tm = fmaxf(fmaxf(s[0][r], s[1][r]), fmaxf(s[2][r], s[3][r]));
      #pragma unroll
      for (int off = 8; off; off >>= 1) tm = fmaxf(tm, __shfl_xor(tm, off));
      float mn = fmaxf(m_r[r], tm);
      alpha[r] = __expf(m_r[r] - mn);
      m_r[r] = mn;
      float rs = 0.f;
      #pragma unroll
      for (int nt = 0; nt < 4; nt++) {
        float pp = __expf(s[nt][r] - mn);
        s[nt][r] = pp;
        rs += pp;
      }
      #pragma unroll
      for (int off = 8; off; off >>= 1) rs += __shfl_xor(rs, off);
      l_r[r] = l_r[r] * alpha[r] + rs;
    }

    #pragma unroll
    for (int nt = 0; nt < 4; nt++)
      #pragma unroll
      for (int r = 0; r < 4; r++)
        Ps[wave][(quad * 4 + r) * 72 + nt * 16 + ln] = f2b(s[nt][r]);
    #pragma unroll
    for (int nt = 0; nt < 4; nt++)
      #pragma unroll
      for (int r = 0; r < 4; r++)
        o[nt][r] *= alpha[r];

    bf16x8 ap0 = *(bf16x8*)&Ps[wave][ln * 72 + quad * 8];
    bf16x8 ap1 = *(bf16x8*)&Ps[wave][ln * 72 + 32 + quad * 8];
    #pragma unroll
    for (int nt = 0; nt < 4; nt++) {
      bf16x8 b0 = *(bf16x8*)&Vs[cur][swz(nt * 16 + ln, quad)];
      bf16x8 b1 = *(bf16x8*)&Vs[cur][swz(nt * 16 + ln, 4 + quad)];
      o[nt] = __builtin_amdgcn_mfma_f32_16x16x32_bf16(ap0, b0, o[nt], 0, 0, 0);
      o[nt] = __builtin_amdgcn_mfma_f32_16x16x32_bf16(ap1, b1, o[nt], 0, 0, 0);
    }

    if (kb < kbe) {
      #pragma unroll
      for (int nt = 0; nt < 4; nt++) {
        c_skv[nt] = n_skv[nt];
        #pragma unroll
        for (int r = 0; r < 4; r++) c_bias[nt][r] = n_bias[nt][r];
      }
    }
    cur ^= 1;
  }

  if (!partial) {
    #pragma unroll
    for (int r = 0; r < 4; r++) {
      float inv = 1.f / l_r[r];
      int qr2 = qrow + r;
      u16* dst = ctx + ((size_t)(b * 512 + qr2)) * 512 + h * 64;
      #pragma unroll
      for (int nt = 0; nt < 4; nt++)
        dst[nt * 16 + ln] = f2b(o[nt][r] * inv);
    }
  } else {
    #pragma unroll
    for (int r = 0; r < 4; r++) {
      int row = qrow + r - 256;
      float* dst = Opart + (((size_t)(part * 64 + bh)) * 256 + row) * 64;
      #pragma unroll
      for (int nt = 0; nt < 4; nt++)
        dst[nt * 16 + ln] = o[nt][r];
    }
    if (ln == 0) {
      #pragma unroll
      for (int r = 0; r < 4; r++) {
        int row = qrow + r - 256;
        float* mp = ml + (((size_t)(part * 64 + bh)) * 256 + row) * 2;
        mp[0] = m_r[r];
        mp[1] = l_r[r];
      }
    }
  }
}

// Compute-stage one 64x64 A-subtile of merged context (rows 256-511 of each b)
// from Opart/ml into swizzled LDS. h = k0>>6 fixed per K-step.
__device__ __forceinline__ void merge_stage(const float* __restrict__ Opart,
                                            const float* __restrict__ mlbuf,
                                            int row0, int k0, u16* dst, int tid) {
  int gi = tid * 2;
  int r = gi >> 3, g = gi & 7;
  int trow = (row0 & 511) - 256 + r;
  int b = row0 >> 9;
  int h = k0 >> 6;
  size_t i0 = ((size_t)(b * 8 + h)) * 256 + trow;
  size_t i1 = i0 + 64 * 256;
  float m0 = mlbuf[i0 * 2], l0 = mlbuf[i0 * 2 + 1];
  float m1 = mlbuf[i1 * 2], l1 = mlbuf[i1 * 2 + 1];
  float m = fmaxf(m0, m1);
  float a0 = __expf(m0 - m), a1 = __expf(m1 - m);
  float linv = 1.f / (l0 * a0 + l1 * a1);
  a0 *= linv; a1 *= linv;
  const float4* p0 = (const float4*)(Opart + i0 * 64 + g * 8);
  const float4* p1 = (const float4*)(Opart + i1 * 64 + g * 8);
  u16x8 q0, q1;
  #pragma unroll
  for (int c = 0; c < 2; c++) {
    float4 x0 = p0[c], x1 = p1[c];
    q0[c * 4 + 0] = f2b(x0.x * a0 + x1.x * a1);
    q0[c * 4 + 1] = f2b(x0.y * a0 + x1.y * a1);
    q0[c * 4 + 2] = f2b(x0.z * a0 + x1.z * a1);
    q0[c * 4 + 3] = f2b(x0.w * a0 + x1.w * a1);
  }
  #pragma unroll
  for (int c = 2; c < 4; c++) {
    float4 x0 = p0[c], x1 = p1[c];
    q1[(c - 2) * 4 + 0] = f2b(x0.x * a0 + x1.x * a1);
    q1[(c - 2) * 4 + 1] = f2b(x0.y * a0 + x1.y * a1);
    q1[(c - 2) * 4 + 2] = f2b(x0.z * a0 + x1.z * a1);
    q1[(c - 2) * 4 + 3] = f2b(x0.w * a0 + x1.w * a1);
  }
  *(u16x8*)&dst[swz(r, g)] = q0;
  *(u16x8*)&dst[swz(r, g + 1)] = q1;
}

// ---------- out GEMM + fused partial-merge: 64x64 tile; grid (64,8)=512 ----------
__global__ __launch_bounds__(256) void out_gemm(const u16* __restrict__ A,
                                                const u16* __restrict__ BT,
                                                const float* __restrict__ Opart,
                                                const float* __restrict__ mlbuf,
                                                float* __restrict__ C) {
  __shared__ alignas(16) u16 As[2][64 * 64];
  __shared__ alignas(16) u16 Bs[2][64 * 64];
  int tid = threadIdx.x;
  int lane = tid & 63, wave = tid >> 6;
  int quad = lane >> 4, ln = lane & 15;
  int wr = wave >> 1, wc = wave & 1;
  int row0 = blockIdx.x * 64;
  int col0 = blockIdx.y * 64;
  bool mergeA = (row0 & 511) >= 256;
  const u16* Ab = A + (size_t)row0 * 512;
  const u16* Bb = BT + (size_t)col0 * 512;

  f32x4 acc[2][2];
  #pragma unroll
  for (int i = 0; i < 2; i++)
    #pragma unroll
    for (int j = 0; j < 2; j++) acc[i][j] = (f32x4){0.f, 0.f, 0.f, 0.f};

  if (mergeA) merge_stage(Opart, mlbuf, row0, 0, As[0], tid);
  else        stage64(Ab, As[0], wave, lane);
  stage64(Bb, Bs[0], wave, lane);

  int cur = 0;
  for (int k0 = 0; k0 < 512; k0 += 64) {
    __syncthreads();
    if (k0 < 448) {
      if (mergeA) merge_stage(Opart, mlbuf, row0, k0 + 64, As[cur ^ 1], tid);
      else        stage64(Ab + k0 + 64, As[cur ^ 1], wave, lane);
      stage64(Bb + k0 + 64, Bs[cur ^ 1], wave, lane);
    }
    #pragma unroll
    for (int s = 0; s < 2; s++) {
      bf16x8 af[2], bfv[2];
      #pragma unroll
      for (int i = 0; i < 2; i++)
        af[i] = *(bf16x8*)&As[cur][swz(wr * 32 + i * 16 + ln, s * 4 + quad)];
      #pragma unroll
      for (int j = 0; j < 2; j++)
        bfv[j] = *(bf16x8*)&Bs[cur][swz(wc * 32 + j * 16 + ln, s * 4 + quad)];
      #pragma unroll
      for (int i = 0; i < 2; i++)
        #pragma unroll
        for (int j = 0; j < 2; j++)
          acc[i][j] = __builtin_amdgcn_mfma_f32_16x16x32_bf16(af[i], bfv[j], acc[i][j], 0, 0, 0);
    }
    cur ^= 1;
  }
  #pragma unroll
  for (int i = 0; i < 2; i++)
    #pragma unroll
    for (int j = 0; j < 2; j++) {
      int mb = row0 + wr * 32 + i * 16 + quad * 4;
      int n = col0 + wc * 32 + j * 16 + ln;
      #pragma unroll
      for (int r = 0; r < 4; r++)
        C[(size_t)(mb + r) * 512 + n] = acc[i][j][r];
    }
}

extern "C" void kernel_launch(void* const* d_in, const int* in_sizes, int n_in,
                              void* d_out, int out_size, void* d_ws, size_t ws_size,
                              hipStream_t stream) {
  const float* states     = (const float*)d_in[0];
  const float* key_states = (const float*)d_in[1];
  const int*   ab         = (const int*)d_in[3];
  const float* Wq         = (const float*)d_in[4];
  const float* Wk         = (const float*)d_in[5];
  const float* Wv         = (const float*)d_in[6];
  const float* Wo         = (const float*)d_in[7];
  const float* be         = (const float*)d_in[8];
  const float* bsc        = (const float*)d_in[9];
  float* out = (float*)d_out;

  char* ws = (char*)d_ws;
  const size_t MB = 1024 * 1024;
  u16* wbase    = (u16*)(ws);                 // 2 MB: wqT|wkT|wvT|woT
  u16* wot      = (u16*)(ws + 1536 * 1024);
  u16* sb       = (u16*)(ws + 2 * MB);        // 4 MB bf16 states
  u16* kbin     = (u16*)(ws + 6 * MB);        // 4 MB bf16 key_states
  u16* qb       = (u16*)(ws + 10 * MB);       // 4 MB
  u16* kbo      = (u16*)(ws + 14 * MB);       // 4 MB
  u16* vtb      = (u16*)(ws + 18 * MB);       // 4 MB (b,h,a,t)
  u16* ctxb     = (u16*)(ws + 22 * MB);       // 4 MB
  float* bias_m = (float*)(ws + 26 * MB);     // 8 MB
  float* summed = (float*)(ws + 34 * MB);     // 128 KB
  float* Opart  = (float*)(ws + 35 * MB);     // 8 MB (2 x 64bh x 256 x 64 f32)
  float* mlbuf  = (float*)(ws + 43 * MB);     // 256 KB

  int n_edges = in_sizes[3] / 4;

  // MEASUREMENT: prologue x6 (idempotent; all precede qkv so bias re-zero OK)
  for (int it = 0; it < 6; ++it)
    prologue<<<dim3(5120), 256, 0, stream>>>(
        states, key_states, Wq, Wk, Wv, Wo, sb, kbin, wbase, bias_m);
  qkv_gemm<<<dim3(64, 12), 256, 0, stream>>>(
      sb, kbin, wbase, ab, be, bsc, bias_m, qb, kbo, vtb, summed, n_edges);
  attn_mfma<<<dim3(768), 256, 0, stream>>>(qb, kbo, vtb, bias_m, summed, ctxb, Opart, mlbuf);
  // MEASUREMENT: out_gemm x6 (idempotent)
  for (int it = 0; it < 6; ++it)
    out_gemm<<<dim3(64, 8), 256, 0, stream>>>(ctxb, wot, Opart, mlbuf, out);
}

// Round 10
// 200.222 us; speedup vs baseline: 1.1940x; 1.1940x over previous
//
#include <hip/hip_runtime.h>

typedef unsigned short u16;
typedef unsigned int u32;
typedef __bf16 bf16x8 __attribute__((ext_vector_type(8)));
typedef float f32x4 __attribute__((ext_vector_type(4)));
typedef u16 u16x8 __attribute__((ext_vector_type(8)));
typedef u16 u16x4 __attribute__((ext_vector_type(4)));

// B=8, N=512, D=512, H=8, DH=64, E=32768, BIAS_DIM=8
// MEASUREMENT ROUND 3 (final): exact R4 chain with qkv_gemm x6 via do_scatter
// flag (scatter only on first launch; GEMM part is a pure function).
// dur = 133.5 + 5*qkv_w. Ledger: attn_w=15.6 (R8), pro_w+out_w=21.1 (R9).
// Decides: qkv-fat (dur>=420) vs cold-state-fat (dur~225-265).

__device__ __forceinline__ u16 f2b(float f) {
  union { float f; u32 i; } v; v.f = f;
  u32 r = v.i + 0x7fffu + ((v.i >> 16) & 1u);
  return (u16)(r >> 16);
}

#define GLL16(gp, lp)                                                      \
  __builtin_amdgcn_global_load_lds(                                       \
      (const __attribute__((address_space(1))) u32*)(gp),                 \
      (__attribute__((address_space(3))) u32*)(lp), 16, 0, 0)

// DMA-stage a 64x64 bf16 tile (row stride 512) into linear LDS; source
// granule pre-swizzled so LDS(r,g) holds global (r, g^(r&7)).
__device__ __forceinline__ void stage64(const u16* g, u16* l, int wave, int lane) {
  int rsub = lane >> 3;
  int gs = (((lane & 7) ^ rsub) << 3);
  #pragma unroll
  for (int c = 0; c < 2; c++) {
    int ch = wave * 2 + c;
    GLL16(g + (size_t)(ch * 8 + rsub) * 512 + gs, l + ch * 512);
  }
}
__device__ __forceinline__ void stage128(const u16* g, u16* l, int wave, int lane) {
  int rsub = lane >> 3;
  int gs = (((lane & 7) ^ rsub) << 3);
  #pragma unroll
  for (int c = 0; c < 4; c++) {
    int ch = wave * 4 + c;
    GLL16(g + (size_t)(ch * 8 + rsub) * 512 + gs, l + ch * 512);
  }
}
// Swizzled read/write offset (elements) into a linear [rows][64] tile.
__device__ __forceinline__ int swz(int row, int g) {
  return row * 64 + ((g ^ (row & 7)) << 3);
}

// ---------- prologue: cvt states/key | transpose 4 weights | zero bias ----------
__global__ __launch_bounds__(256) void prologue(
    const float* __restrict__ states, const float* __restrict__ key_states,
    const float* __restrict__ Wq, const float* __restrict__ Wk,
    const float* __restrict__ Wv, const float* __restrict__ Wo,
    u16* __restrict__ sb, u16* __restrict__ kbin, u16* __restrict__ wbase,
    float* __restrict__ bias_mat) {
  __shared__ u16 t[32][33];
  int bid = blockIdx.x;
  int tid = threadIdx.x;
  if (bid < 2048) {
    const float* src = (bid >= 1024) ? key_states : states;
    u16* dst = (bid >= 1024) ? kbin : sb;
    int gid = (bid & 1023) * 256 + tid;
    const float4* sp = (const float4*)src + (size_t)gid * 2;
    float4 x0 = sp[0], x1 = sp[1];
    u16x8 p;
    p[0] = f2b(x0.x); p[1] = f2b(x0.y); p[2] = f2b(x0.z); p[3] = f2b(x0.w);
    p[4] = f2b(x1.x); p[5] = f2b(x1.y); p[6] = f2b(x1.z); p[7] = f2b(x1.w);
    *(u16x8*)(dst + (size_t)gid * 8) = p;
  } else if (bid < 3072) {
    int tt = bid - 2048;
    int z = tt >> 8, rem = tt & 255;
    int bx = rem & 15, by = rem >> 4;
    const float* src; float sc = 1.f;
    if (z == 0)      { src = Wq; sc = 0.125f; }
    else if (z == 1) { src = Wk; }
    else if (z == 2) { src = Wv; }
    else             { src = Wo; }
    u16* dst = wbase + (size_t)z * 262144;
    int tx = tid & 31, ty = tid >> 5;
    int c0 = bx * 32, r0 = by * 32;
    #pragma unroll
    for (int i = ty; i < 32; i += 8) t[i][tx] = f2b(src[(r0 + i) * 512 + c0 + tx] * sc);
    __syncthreads();
    #pragma unroll
    for (int i = ty; i < 32; i += 8) dst[(c0 + i) * 512 + r0 + tx] = t[tx][i];
  } else {
    int i = (bid - 3072) * 256 + tid;
    float4 z4 = {0.f, 0.f, 0.f, 0.f};
    ((float4*)bias_mat)[i] = z4;
  }
}

// ---------- fused QKV GEMM + edge-bias scatter; grid (64,12)=768 ----------
__global__ __launch_bounds__(256) void qkv_gemm(const u16* __restrict__ sb,
                                                const u16* __restrict__ kbin,
                                                const u16* __restrict__ wT,
                                                const int* __restrict__ ab,
                                                const float* __restrict__ be,
                                                const float* __restrict__ bsc,
                                                float* __restrict__ bias_m,
                                                u16* __restrict__ qb,
                                                u16* __restrict__ kbo,
                                                u16* __restrict__ vtb,
                                                float* __restrict__ summed,
                                                int n_edges, int do_scatter) {
  __shared__ alignas(16) u16 As[2][64 * 64];
  __shared__ alignas(16) u16 Bs[2][128 * 64];
  __shared__ float ssum[4][64];
  __shared__ float tvs[8];
  int tid = threadIdx.x;
  int lane = tid & 63, wave = tid >> 6;
  int quad = lane >> 4, ln = lane & 15;
  int fb = blockIdx.y * 64 + blockIdx.x;

  if (do_scatter) {
    if (tid < 8) {
      const float4* bev = (const float4*)(be + tid * 64);
      const float4* bscv = (const float4*)bsc;
      float s = 0.f;
      #pragma unroll
      for (int a4 = 0; a4 < 16; a4++) {
        float4 x = bev[a4], y = bscv[a4];
        s += x.x * y.x + x.y * y.y + x.z * y.z + x.w * y.w;
      }
      tvs[tid] = s * 0.125f;
    }
    __syncthreads();
    for (int e = fb * 256 + tid; e < n_edges; e += 768 * 256) {
      int et = ab[e * 4 + 0];
      int b  = ab[e * 4 + 1];
      int qi = ab[e * 4 + 2];
      int ki = ab[e * 4 + 3];
      atomicAdd(&bias_m[((size_t)b * 512 + qi) * 512 + ki], tvs[et]);
    }
  }

  int row0 = blockIdx.x * 64;
  int col0 = blockIdx.y * 128;
  const u16* A = (col0 < 512) ? sb : kbin;
  const u16* Ab = A + (size_t)row0 * 512;
  const u16* Bb = wT + (size_t)col0 * 512;

  f32x4 acc[4][2];
  #pragma unroll
  for (int i = 0; i < 4; i++)
    #pragma unroll
    for (int j = 0; j < 2; j++) acc[i][j] = (f32x4){0.f, 0.f, 0.f, 0.f};

  stage64(Ab, As[0], wave, lane);
  stage128(Bb, Bs[0], wave, lane);

  int cur = 0;
  for (int k0 = 0; k0 < 512; k0 += 64) {
    __syncthreads();
    if (k0 < 448) {
      stage64(Ab + k0 + 64, As[cur ^ 1], wave, lane);
      stage128(Bb + k0 + 64, Bs[cur ^ 1], wave, lane);
    }
    #pragma unroll
    for (int s = 0; s < 2; s++) {
      bf16x8 af[4], bfv[2];
      #pragma unroll
      for (int i = 0; i < 4; i++)
        af[i] = *(bf16x8*)&As[cur][swz(i * 16 + ln, s * 4 + quad)];
      #pragma unroll
      for (int j = 0; j < 2; j++)
        bfv[j] = *(bf16x8*)&Bs[cur][swz(wave * 32 + j * 16 + ln, s * 4 + quad)];
      #pragma unroll
      for (int i = 0; i < 4; i++)
        #pragma unroll
        for (int j = 0; j < 2; j++)
          acc[i][j] = __builtin_amdgcn_mfma_f32_16x16x32_bf16(af[i], bfv[j], acc[i][j], 0, 0, 0);
    }
    cur ^= 1;
  }

  int region = col0 >> 9;
  int nbase = col0 & 511;
  if (region <= 1) {
    u16* Cout = region ? kbo : qb;
    #pragma unroll
    for (int i = 0; i < 4; i++)
      #pragma unroll
      for (int j = 0; j < 2; j++) {
        int mb = row0 + i * 16 + quad * 4;
        int n = nbase + wave * 32 + j * 16 + ln;
        #pragma unroll
        for (int r = 0; r < 4; r++)
          Cout[(size_t)(mb + r) * 512 + n] = f2b(acc[i][j][r]);
      }
    if (region == 1) {
      #pragma unroll
      for (int i = 0; i < 4; i++)
        #pragma unroll
        for (int r = 0; r < 4; r++) {
          float v = acc[i][0][r] + acc[i][1][r];
          v += __shfl_xor(v, 1);
          v += __shfl_xor(v, 2);
          v += __shfl_xor(v, 4);
          v += __shfl_xor(v, 8);
          if (ln == 0) ssum[wave][i * 16 + quad * 4 + r] = v;
        }
      __syncthreads();
      if (tid < 128) {
        int hl = tid >> 6, row = tid & 63;
        float s = ssum[hl * 2][row] + ssum[hl * 2 + 1][row];
        int m = row0 + row;
        int b = m >> 9, t = m & 511;
        int h = (nbase >> 6) + hl;
        summed[((size_t)(b * 8 + h)) * 512 + t] = s;
      }
    }
  } else {
    #pragma unroll
    for (int i = 0; i < 4; i++)
      #pragma unroll
      for (int j = 0; j < 2; j++) {
        int mb = row0 + i * 16 + quad * 4;
        int bb = mb >> 9, t0 = mb & 511;
        int a_abs = nbase + wave * 32 + j * 16 + ln;
        int h = a_abs >> 6, a = a_abs & 63;
        u16x4 p;
        p[0] = f2b(acc[i][j][0]); p[1] = f2b(acc[i][j][1]);
        p[2] = f2b(acc[i][j][2]); p[3] = f2b(acc[i][j][3]);
        *(u16x4*)&vtb[(((size_t)bb * 8 + h) * 64 + a) * 512 + t0] = p;
      }
  }
}

// ---------- MFMA flash attention, decode-split, CU-balanced permutation ----------
__global__ __launch_bounds__(256) void attn_mfma(const u16* __restrict__ q,
                                                 const u16* __restrict__ k,
                                                 const u16* __restrict__ vt,
                                                 const float* __restrict__ bias_mat,
                                                 const float* __restrict__ summed,
                                                 u16* __restrict__ ctx,
                                                 float* __restrict__ Opart,
                                                 float* __restrict__ ml) {
  __shared__ alignas(16) u16 Qs[64 * 64];
  __shared__ alignas(16) u16 Ks[2][64 * 64];
  __shared__ alignas(16) u16 Vs[2][64 * 64];
  __shared__ alignas(16) u16 Ps[4][16 * 72];
  int tid = threadIdx.x;
  int wave = tid >> 6, lane = tid & 63;
  int quad = lane >> 4, ln = lane & 15;
  int p2 = blockIdx.x;
  int bh, u;
  {
    const int fours[6] = {3, 4, 6, 8, 10, 11};
    const int threes[2] = {2, 9};
    const int ones[2] = {0, 5};
    const int twos[2] = {1, 7};
    if (p2 < 384)      { bh = p2 & 63; u = fours[p2 >> 6]; }
    else if (p2 < 512) { int q2 = p2 - 384; bh = q2 & 63; u = threes[q2 >> 6]; }
    else if (p2 < 640) { int q2 = p2 - 512; bh = q2 & 63; u = ones[q2 >> 6]; }
    else               { int q2 = p2 - 640; bh = q2 & 63; u = twos[q2 >> 6]; }
  }
  int b = bh >> 3, h = bh & 7;
  int qt, kb0, kbe, part = 0;
  bool partial;
  if (u < 4) { qt = u; kb0 = 0; kbe = u; partial = false; }
  else {
    int v = u - 4; qt = 4 + (v >> 1); part = v & 1; partial = true;
    if (part == 0) { kb0 = 0; kbe = 3; } else { kb0 = 4; kbe = qt; }
  }
  int q0 = qt * 64;

  const u16* qb_ = q + ((size_t)(b * 512 + q0)) * 512 + h * 64;
  const u16* kb_ = k + ((size_t)(b * 512)) * 512 + h * 64;
  const u16* vb_ = vt + ((size_t)bh * 64) * 512;

  stage64(qb_, Qs, wave, lane);
  stage64(kb_ + (size_t)kb0 * 64 * 512, Ks[0], wave, lane);
  stage64(vb_ + kb0 * 64, Vs[0], wave, lane);

  float m_r[4], l_r[4];
  f32x4 o[4];
  #pragma unroll
  for (int r = 0; r < 4; r++) { m_r[r] = -3.40282347e38f; l_r[r] = 0.f; }
  #pragma unroll
  for (int nt = 0; nt < 4; nt++) o[nt] = (f32x4){0.f, 0.f, 0.f, 0.f};

  int qrow = q0 + wave * 16 + quad * 4;

  float c_skv[4], c_bias[4][4];
  #pragma unroll
  for (int nt = 0; nt < 4; nt++) {
    int t = kb0 * 64 + nt * 16 + ln;
    c_skv[nt] = summed[bh * 512 + t];
    const float* bp2 = bias_mat + ((size_t)(b * 512 + qrow)) * 512 + t;
    #pragma unroll
    for (int r = 0; r < 4; r++) c_bias[nt][r] = bp2[(size_t)r * 512];
  }

  int cur = 0;
  for (int kb = kb0; kb <= kbe; kb++) {
    __syncthreads();

    float n_skv[4], n_bias[4][4];
    if (kb < kbe) {
      stage64(kb_ + (size_t)(kb + 1) * 64 * 512, Ks[cur ^ 1], wave, lane);
      stage64(vb_ + (kb + 1) * 64, Vs[cur ^ 1], wave, lane);
      #pragma unroll
      for (int nt = 0; nt < 4; nt++) {
        int t = (kb + 1) * 64 + nt * 16 + ln;
        n_skv[nt] = summed[bh * 512 + t];
        const float* bp2 = bias_mat + ((size_t)(b * 512 + qrow)) * 512 + t;
        #pragma unroll
        for (int r = 0; r < 4; r++) n_bias[nt][r] = bp2[(size_t)r * 512];
      }
    }

    bf16x8 aq0 = *(bf16x8*)&Qs[swz(wave * 16 + ln, quad)];
    bf16x8 aq1 = *(bf16x8*)&Qs[swz(wave * 16 + ln, 4 + quad)];
    f32x4 s[4];
    #pragma unroll
    for (int nt = 0; nt < 4; nt++) {
      bf16x8 b0 = *(bf16x8*)&Ks[cur][swz(nt * 16 + ln, quad)];
      bf16x8 b1 = *(bf16x8*)&Ks[cur][swz(nt * 16 + ln, 4 + quad)];
      s[nt] = (f32x4){0.f, 0.f, 0.f, 0.f};
      s[nt] = __builtin_amdgcn_mfma_f32_16x16x32_bf16(aq0, b0, s[nt], 0, 0, 0);
      s[nt] = __builtin_amdgcn_mfma_f32_16x16x32_bf16(aq1, b1, s[nt], 0, 0, 0);
    }

    #pragma unroll
    for (int nt = 0; nt < 4; nt++) {
      int t = kb * 64 + nt * 16 + ln;
      #pragma unroll
      for (int r = 0; r < 4; r++) {
        float val = s[nt][r] + c_bias[nt][r] * c_skv[nt];
        s[nt][r] = (t <= qrow + r) ? val : -3.40282347e38f;
      }
    }

    float alpha[4];
    #pragma unroll
    for (int r = 0; r < 4; r++) {
      float tm = fmaxf(fmaxf(s[0][r], s[1][r]), fmaxf(s[2][r], s[3][r]));
      #pragma unroll
      for (int off = 8; off; off >>= 1) tm = fmaxf(tm, __shfl_xor(tm, off));
      float mn = fmaxf(m_r[r], tm);
      alpha[r] = __expf(m_r[r] - mn);
      m_r[r] = mn;
      float rs = 0.f;
      #pragma unroll
      for (int nt = 0; nt < 4; nt++) {
        float pp = __expf(s[nt][r] - mn);
        s[nt][r] = pp;
        rs += pp;
      }
      #pragma unroll
      for (int off = 8; off; off >>= 1) rs += __shfl_xor(rs, off);
      l_r[r] = l_r[r] * alpha[r] + rs;
    }

    #pragma unroll
    for (int nt = 0; nt < 4; nt++)
      #pragma unroll
      for (int r = 0; r < 4; r++)
        Ps[wave][(quad * 4 + r) * 72 + nt * 16 + ln] = f2b(s[nt][r]);
    #pragma unroll
    for (int nt = 0; nt < 4; nt++)
      #pragma unroll
      for (int r = 0; r < 4; r++)
        o[nt][r] *= alpha[r];

    bf16x8 ap0 = *(bf16x8*)&Ps[wave][ln * 72 + quad * 8];
    bf16x8 ap1 = *(bf16x8*)&Ps[wave][ln * 72 + 32 + quad * 8];
    #pragma unroll
    for (int nt = 0; nt < 4; nt++) {
      bf16x8 b0 = *(bf16x8*)&Vs[cur][swz(nt * 16 + ln, quad)];
      bf16x8 b1 = *(bf16x8*)&Vs[cur][swz(nt * 16 + ln, 4 + quad)];
      o[nt] = __builtin_amdgcn_mfma_f32_16x16x32_bf16(ap0, b0, o[nt], 0, 0, 0);
      o[nt] = __builtin_amdgcn_mfma_f32_16x16x32_bf16(ap1, b1, o[nt], 0, 0, 0);
    }

    if (kb < kbe) {
      #pragma unroll
      for (int nt = 0; nt < 4; nt++) {
        c_skv[nt] = n_skv[nt];
        #pragma unroll
        for (int r = 0; r < 4; r++) c_bias[nt][r] = n_bias[nt][r];
      }
    }
    cur ^= 1;
  }

  if (!partial) {
    #pragma unroll
    for (int r = 0; r < 4; r++) {
      float inv = 1.f / l_r[r];
      int qr2 = qrow + r;
      u16* dst = ctx + ((size_t)(b * 512 + qr2)) * 512 + h * 64;
      #pragma unroll
      for (int nt = 0; nt < 4; nt++)
        dst[nt * 16 + ln] = f2b(o[nt][r] * inv);
    }
  } else {
    #pragma unroll
    for (int r = 0; r < 4; r++) {
      int row = qrow + r - 256;
      float* dst = Opart + (((size_t)(part * 64 + bh)) * 256 + row) * 64;
      #pragma unroll
      for (int nt = 0; nt < 4; nt++)
        dst[nt * 16 + ln] = o[nt][r];
    }
    if (ln == 0) {
      #pragma unroll
      for (int r = 0; r < 4; r++) {
        int row = qrow + r - 256;
        float* mp = ml + (((size_t)(part * 64 + bh)) * 256 + row) * 2;
        mp[0] = m_r[r];
        mp[1] = l_r[r];
      }
    }
  }
}

// Compute-stage one 64x64 A-subtile of merged context (rows 256-511 of each b)
// from Opart/ml into swizzled LDS. h = k0>>6 fixed per K-step.
__device__ __forceinline__ void merge_stage(const float* __restrict__ Opart,
                                            const float* __restrict__ mlbuf,
                                            int row0, int k0, u16* dst, int tid) {
  int gi = tid * 2;
  int r = gi >> 3, g = gi & 7;
  int trow = (row0 & 511) - 256 + r;
  int b = row0 >> 9;
  int h = k0 >> 6;
  size_t i0 = ((size_t)(b * 8 + h)) * 256 + trow;
  size_t i1 = i0 + 64 * 256;
  float m0 = mlbuf[i0 * 2], l0 = mlbuf[i0 * 2 + 1];
  float m1 = mlbuf[i1 * 2], l1 = mlbuf[i1 * 2 + 1];
  float m = fmaxf(m0, m1);
  float a0 = __expf(m0 - m), a1 = __expf(m1 - m);
  float linv = 1.f / (l0 * a0 + l1 * a1);
  a0 *= linv; a1 *= linv;
  const float4* p0 = (const float4*)(Opart + i0 * 64 + g * 8);
  const float4* p1 = (const float4*)(Opart + i1 * 64 + g * 8);
  u16x8 q0, q1;
  #pragma unroll
  for (int c = 0; c < 2; c++) {
    float4 x0 = p0[c], x1 = p1[c];
    q0[c * 4 + 0] = f2b(x0.x * a0 + x1.x * a1);
    q0[c * 4 + 1] = f2b(x0.y * a0 + x1.y * a1);
    q0[c * 4 + 2] = f2b(x0.z * a0 + x1.z * a1);
    q0[c * 4 + 3] = f2b(x0.w * a0 + x1.w * a1);
  }
  #pragma unroll
  for (int c = 2; c < 4; c++) {
    float4 x0 = p0[c], x1 = p1[c];
    q1[(c - 2) * 4 + 0] = f2b(x0.x * a0 + x1.x * a1);
    q1[(c - 2) * 4 + 1] = f2b(x0.y * a0 + x1.y * a1);
    q1[(c - 2) * 4 + 2] = f2b(x0.z * a0 + x1.z * a1);
    q1[(c - 2) * 4 + 3] = f2b(x0.w * a0 + x1.w * a1);
  }
  *(u16x8*)&dst[swz(r, g)] = q0;
  *(u16x8*)&dst[swz(r, g + 1)] = q1;
}

// ---------- out GEMM + fused partial-merge: 64x64 tile; grid (64,8)=512 ----------
__global__ __launch_bounds__(256) void out_gemm(const u16* __restrict__ A,
                                                const u16* __restrict__ BT,
                                                const float* __restrict__ Opart,
                                                const float* __restrict__ mlbuf,
                                                float* __restrict__ C) {
  __shared__ alignas(16) u16 As[2][64 * 64];
  __shared__ alignas(16) u16 Bs[2][64 * 64];
  int tid = threadIdx.x;
  int lane = tid & 63, wave = tid >> 6;
  int quad = lane >> 4, ln = lane & 15;
  int wr = wave >> 1, wc = wave & 1;
  int row0 = blockIdx.x * 64;
  int col0 = blockIdx.y * 64;
  bool mergeA = (row0 & 511) >= 256;
  const u16* Ab = A + (size_t)row0 * 512;
  const u16* Bb = BT + (size_t)col0 * 512;

  f32x4 acc[2][2];
  #pragma unroll
  for (int i = 0; i < 2; i++)
    #pragma unroll
    for (int j = 0; j < 2; j++) acc[i][j] = (f32x4){0.f, 0.f, 0.f, 0.f};

  if (mergeA) merge_stage(Opart, mlbuf, row0, 0, As[0], tid);
  else        stage64(Ab, As[0], wave, lane);
  stage64(Bb, Bs[0], wave, lane);

  int cur = 0;
  for (int k0 = 0; k0 < 512; k0 += 64) {
    __syncthreads();
    if (k0 < 448) {
      if (mergeA) merge_stage(Opart, mlbuf, row0, k0 + 64, As[cur ^ 1], tid);
      else        stage64(Ab + k0 + 64, As[cur ^ 1], wave, lane);
      stage64(Bb + k0 + 64, Bs[cur ^ 1], wave, lane);
    }
    #pragma unroll
    for (int s = 0; s < 2; s++) {
      bf16x8 af[2], bfv[2];
      #pragma unroll
      for (int i = 0; i < 2; i++)
        af[i] = *(bf16x8*)&As[cur][swz(wr * 32 + i * 16 + ln, s * 4 + quad)];
      #pragma unroll
      for (int j = 0; j < 2; j++)
        bfv[j] = *(bf16x8*)&Bs[cur][swz(wc * 32 + j * 16 + ln, s * 4 + quad)];
      #pragma unroll
      for (int i = 0; i < 2; i++)
        #pragma unroll
        for (int j = 0; j < 2; j++)
          acc[i][j] = __builtin_amdgcn_mfma_f32_16x16x32_bf16(af[i], bfv[j], acc[i][j], 0, 0, 0);
    }
    cur ^= 1;
  }
  #pragma unroll
  for (int i = 0; i < 2; i++)
    #pragma unroll
    for (int j = 0; j < 2; j++) {
      int mb = row0 + wr * 32 + i * 16 + quad * 4;
      int n = col0 + wc * 32 + j * 16 + ln;
      #pragma unroll
      for (int r = 0; r < 4; r++)
        C[(size_t)(mb + r) * 512 + n] = acc[i][j][r];
    }
}

extern "C" void kernel_launch(void* const* d_in, const int* in_sizes, int n_in,
                              void* d_out, int out_size, void* d_ws, size_t ws_size,
                              hipStream_t stream) {
  const float* states     = (const float*)d_in[0];
  const float* key_states = (const float*)d_in[1];
  const int*   ab         = (const int*)d_in[3];
  const float* Wq         = (const float*)d_in[4];
  const float* Wk         = (const float*)d_in[5];
  const float* Wv         = (const float*)d_in[6];
  const float* Wo         = (const float*)d_in[7];
  const float* be         = (const float*)d_in[8];
  const float* bsc        = (const float*)d_in[9];
  float* out = (float*)d_out;

  char* ws = (char*)d_ws;
  const size_t MB = 1024 * 1024;
  u16* wbase    = (u16*)(ws);                 // 2 MB: wqT|wkT|wvT|woT
  u16* wot      = (u16*)(ws + 1536 * 1024);
  u16* sb       = (u16*)(ws + 2 * MB);        // 4 MB bf16 states
  u16* kbin     = (u16*)(ws + 6 * MB);        // 4 MB bf16 key_states
  u16* qb       = (u16*)(ws + 10 * MB);       // 4 MB
  u16* kbo      = (u16*)(ws + 14 * MB);       // 4 MB
  u16* vtb      = (u16*)(ws + 18 * MB);       // 4 MB (b,h,a,t)
  u16* ctxb     = (u16*)(ws + 22 * MB);       // 4 MB
  float* bias_m = (float*)(ws + 26 * MB);     // 8 MB
  float* summed = (float*)(ws + 34 * MB);     // 128 KB
  float* Opart  = (float*)(ws + 35 * MB);     // 8 MB (2 x 64bh x 256 x 64 f32)
  float* mlbuf  = (float*)(ws + 43 * MB);     // 256 KB

  int n_edges = in_sizes[3] / 4;

  prologue<<<dim3(5120), 256, 0, stream>>>(
      states, key_states, Wq, Wk, Wv, Wo, sb, kbin, wbase, bias_m);
  // MEASUREMENT: qkv x6. Scatter only on the first launch (bias_m is
  // accumulate-once); the GEMM portion is a pure function -> idempotent.
  qkv_gemm<<<dim3(64, 12), 256, 0, stream>>>(
      sb, kbin, wbase, ab, be, bsc, bias_m, qb, kbo, vtb, summed, n_edges, 1);
  for (int it = 0; it < 5; ++it)
    qkv_gemm<<<dim3(64, 12), 256, 0, stream>>>(
        sb, kbin, wbase, ab, be, bsc, bias_m, qb, kbo, vtb, summed, n_edges, 0);
  attn_mfma<<<dim3(768), 256, 0, stream>>>(qb, kbo, vtb, bias_m, summed, ctxb, Opart, mlbuf);
  out_gemm<<<dim3(64, 8), 256, 0, stream>>>(ctxb, wot, Opart, mlbuf, out);
}

// Round 11
// 130.573 us; speedup vs baseline: 1.8309x; 1.5334x over previous
//
#include <hip/hip_runtime.h>

typedef unsigned short u16;
typedef unsigned int u32;
typedef __bf16 bf16x8 __attribute__((ext_vector_type(8)));
typedef float f32x4 __attribute__((ext_vector_type(4)));
typedef u16 u16x8 __attribute__((ext_vector_type(8)));
typedef u16 u16x4 __attribute__((ext_vector_type(4)));

// B=8, N=512, D=512, H=8, DH=64, E=32768, BIAS_DIM=8
// R11: footprint-reduction round. Ledger (R8-R10 warm marginals): attn 15.6,
// pro+out 21.1, qkv 13.3 => sum ~50us vs chain 133.5 => ~83us is COLD-state
// (poisoned-workspace eviction + per-stage cold misses + boundary L2 flushes).
// Changes: (1) decode-split removed — attn = 512 blocks, one per (b,h,qt),
// full causal range; pairing (8+1)(7+2)(6+3)(5+4)=9 tiles/CU keeps balance;
// Opart/ml/merge deleted (-8MB cold writes, -64MB L3 re-reads in out_gemm).
// (2) ctxb aliases sb (dead after qkv): unique footprint 46->30MB.
// (3) causally-masked edges (ki>qi) skipped in scatter.

__device__ __forceinline__ u16 f2b(float f) {
  union { float f; u32 i; } v; v.f = f;
  u32 r = v.i + 0x7fffu + ((v.i >> 16) & 1u);
  return (u16)(r >> 16);
}

#define GLL16(gp, lp)                                                      \
  __builtin_amdgcn_global_load_lds(                                       \
      (const __attribute__((address_space(1))) u32*)(gp),                 \
      (__attribute__((address_space(3))) u32*)(lp), 16, 0, 0)

// DMA-stage a 64x64 bf16 tile (row stride 512) into linear LDS; source
// granule pre-swizzled so LDS(r,g) holds global (r, g^(r&7)).
__device__ __forceinline__ void stage64(const u16* g, u16* l, int wave, int lane) {
  int rsub = lane >> 3;
  int gs = (((lane & 7) ^ rsub) << 3);
  #pragma unroll
  for (int c = 0; c < 2; c++) {
    int ch = wave * 2 + c;
    GLL16(g + (size_t)(ch * 8 + rsub) * 512 + gs, l + ch * 512);
  }
}
__device__ __forceinline__ void stage128(const u16* g, u16* l, int wave, int lane) {
  int rsub = lane >> 3;
  int gs = (((lane & 7) ^ rsub) << 3);
  #pragma unroll
  for (int c = 0; c < 4; c++) {
    int ch = wave * 4 + c;
    GLL16(g + (size_t)(ch * 8 + rsub) * 512 + gs, l + ch * 512);
  }
}
// Swizzled read/write offset (elements) into a linear [rows][64] tile.
__device__ __forceinline__ int swz(int row, int g) {
  return row * 64 + ((g ^ (row & 7)) << 3);
}

// ---------- prologue: cvt states/key | transpose 4 weights | zero bias ----------
__global__ __launch_bounds__(256) void prologue(
    const float* __restrict__ states, const float* __restrict__ key_states,
    const float* __restrict__ Wq, const float* __restrict__ Wk,
    const float* __restrict__ Wv, const float* __restrict__ Wo,
    u16* __restrict__ sb, u16* __restrict__ kbin, u16* __restrict__ wbase,
    float* __restrict__ bias_mat) {
  __shared__ u16 t[32][33];
  int bid = blockIdx.x;
  int tid = threadIdx.x;
  if (bid < 2048) {
    const float* src = (bid >= 1024) ? key_states : states;
    u16* dst = (bid >= 1024) ? kbin : sb;
    int gid = (bid & 1023) * 256 + tid;
    const float4* sp = (const float4*)src + (size_t)gid * 2;
    float4 x0 = sp[0], x1 = sp[1];
    u16x8 p;
    p[0] = f2b(x0.x); p[1] = f2b(x0.y); p[2] = f2b(x0.z); p[3] = f2b(x0.w);
    p[4] = f2b(x1.x); p[5] = f2b(x1.y); p[6] = f2b(x1.z); p[7] = f2b(x1.w);
    *(u16x8*)(dst + (size_t)gid * 8) = p;
  } else if (bid < 3072) {
    int tt = bid - 2048;
    int z = tt >> 8, rem = tt & 255;
    int bx = rem & 15, by = rem >> 4;
    const float* src; float sc = 1.f;
    if (z == 0)      { src = Wq; sc = 0.125f; }
    else if (z == 1) { src = Wk; }
    else if (z == 2) { src = Wv; }
    else             { src = Wo; }
    u16* dst = wbase + (size_t)z * 262144;
    int tx = tid & 31, ty = tid >> 5;
    int c0 = bx * 32, r0 = by * 32;
    #pragma unroll
    for (int i = ty; i < 32; i += 8) t[i][tx] = f2b(src[(r0 + i) * 512 + c0 + tx] * sc);
    __syncthreads();
    #pragma unroll
    for (int i = ty; i < 32; i += 8) dst[(c0 + i) * 512 + r0 + tx] = t[tx][i];
  } else {
    int i = (bid - 3072) * 256 + tid;
    float4 z4 = {0.f, 0.f, 0.f, 0.f};
    ((float4*)bias_mat)[i] = z4;
  }
}

// ---------- fused QKV GEMM + edge-bias scatter; grid (64,12)=768 ----------
// M=4096, N=1536 (regions: q | k | v), K=512. v written TRANSPOSED into vtb.
// k-region blocks emit summed[(b*8+h)*512+t] = sum_a k.
__global__ __launch_bounds__(256) void qkv_gemm(const u16* __restrict__ sb,
                                                const u16* __restrict__ kbin,
                                                const u16* __restrict__ wT,
                                                const int* __restrict__ ab,
                                                const float* __restrict__ be,
                                                const float* __restrict__ bsc,
                                                float* __restrict__ bias_m,
                                                u16* __restrict__ qb,
                                                u16* __restrict__ kbo,
                                                u16* __restrict__ vtb,
                                                float* __restrict__ summed,
                                                int n_edges) {
  __shared__ alignas(16) u16 As[2][64 * 64];
  __shared__ alignas(16) u16 Bs[2][128 * 64];
  __shared__ float ssum[4][64];
  __shared__ float tvs[8];
  int tid = threadIdx.x;
  int lane = tid & 63, wave = tid >> 6;
  int quad = lane >> 4, ln = lane & 15;
  int fb = blockIdx.y * 64 + blockIdx.x;

  if (tid < 8) {
    const float4* bev = (const float4*)(be + tid * 64);
    const float4* bscv = (const float4*)bsc;
    float s = 0.f;
    #pragma unroll
    for (int a4 = 0; a4 < 16; a4++) {
      float4 x = bev[a4], y = bscv[a4];
      s += x.x * y.x + x.y * y.y + x.z * y.z + x.w * y.w;
    }
    tvs[tid] = s * 0.125f;
  }
  __syncthreads();
  for (int e = fb * 256 + tid; e < n_edges; e += 768 * 256) {
    int et = ab[e * 4 + 0];
    int b  = ab[e * 4 + 1];
    int qi = ab[e * 4 + 2];
    int ki = ab[e * 4 + 3];
    if (ki <= qi)   // upper-triangle edges are causally masked — never read
      atomicAdd(&bias_m[((size_t)b * 512 + qi) * 512 + ki], tvs[et]);
  }

  int row0 = blockIdx.x * 64;
  int col0 = blockIdx.y * 128;
  const u16* A = (col0 < 512) ? sb : kbin;
  const u16* Ab = A + (size_t)row0 * 512;
  const u16* Bb = wT + (size_t)col0 * 512;

  f32x4 acc[4][2];
  #pragma unroll
  for (int i = 0; i < 4; i++)
    #pragma unroll
    for (int j = 0; j < 2; j++) acc[i][j] = (f32x4){0.f, 0.f, 0.f, 0.f};

  stage64(Ab, As[0], wave, lane);
  stage128(Bb, Bs[0], wave, lane);

  int cur = 0;
  for (int k0 = 0; k0 < 512; k0 += 64) {
    __syncthreads();   // drains buf[cur] DMAs; protects WAR on buf[cur^1]
    if (k0 < 448) {
      stage64(Ab + k0 + 64, As[cur ^ 1], wave, lane);
      stage128(Bb + k0 + 64, Bs[cur ^ 1], wave, lane);
    }
    #pragma unroll
    for (int s = 0; s < 2; s++) {
      bf16x8 af[4], bfv[2];
      #pragma unroll
      for (int i = 0; i < 4; i++)
        af[i] = *(bf16x8*)&As[cur][swz(i * 16 + ln, s * 4 + quad)];
      #pragma unroll
      for (int j = 0; j < 2; j++)
        bfv[j] = *(bf16x8*)&Bs[cur][swz(wave * 32 + j * 16 + ln, s * 4 + quad)];
      #pragma unroll
      for (int i = 0; i < 4; i++)
        #pragma unroll
        for (int j = 0; j < 2; j++)
          acc[i][j] = __builtin_amdgcn_mfma_f32_16x16x32_bf16(af[i], bfv[j], acc[i][j], 0, 0, 0);
    }
    cur ^= 1;
  }

  int region = col0 >> 9;
  int nbase = col0 & 511;
  if (region <= 1) {
    u16* Cout = region ? kbo : qb;
    #pragma unroll
    for (int i = 0; i < 4; i++)
      #pragma unroll
      for (int j = 0; j < 2; j++) {
        int mb = row0 + i * 16 + quad * 4;
        int n = nbase + wave * 32 + j * 16 + ln;
        #pragma unroll
        for (int r = 0; r < 4; r++)
          Cout[(size_t)(mb + r) * 512 + n] = f2b(acc[i][j][r]);
      }
    if (region == 1) {
      #pragma unroll
      for (int i = 0; i < 4; i++)
        #pragma unroll
        for (int r = 0; r < 4; r++) {
          float v = acc[i][0][r] + acc[i][1][r];
          v += __shfl_xor(v, 1);
          v += __shfl_xor(v, 2);
          v += __shfl_xor(v, 4);
          v += __shfl_xor(v, 8);
          if (ln == 0) ssum[wave][i * 16 + quad * 4 + r] = v;
        }
      __syncthreads();
      if (tid < 128) {
        int hl = tid >> 6, row = tid & 63;
        float s = ssum[hl * 2][row] + ssum[hl * 2 + 1][row];
        int m = row0 + row;
        int b = m >> 9, t = m & 511;
        int h = (nbase >> 6) + hl;
        summed[((size_t)(b * 8 + h)) * 512 + t] = s;
      }
    }
  } else {
    #pragma unroll
    for (int i = 0; i < 4; i++)
      #pragma unroll
      for (int j = 0; j < 2; j++) {
        int mb = row0 + i * 16 + quad * 4;
        int bb = mb >> 9, t0 = mb & 511;
        int a_abs = nbase + wave * 32 + j * 16 + ln;
        int h = a_abs >> 6, a = a_abs & 63;
        u16x4 p;
        p[0] = f2b(acc[i][j][0]); p[1] = f2b(acc[i][j][1]);
        p[2] = f2b(acc[i][j][2]); p[3] = f2b(acc[i][j][3]);
        *(u16x4*)&vtb[(((size_t)bb * 8 + h) * 64 + a) * 512 + t0] = p;
      }
  }
}

// ---------- MFMA flash attention, single-pass causal; grid 512 ----------
// Block p<256: (bh=p&63, qt=7-(p>>6)); p>=256: (bh, qt=(p-256)>>6).
// Under round-robin p->CU, CU c gets qt pairs (8+1),(7+2),(6+3),(5+4)
// = 9 k-tiles per CU — same balance as the old decode-split, no partials.
__global__ __launch_bounds__(256) void attn_mfma(const u16* __restrict__ q,
                                                 const u16* __restrict__ k,
                                                 const u16* __restrict__ vt,
                                                 const float* __restrict__ bias_mat,
                                                 const float* __restrict__ summed,
                                                 u16* __restrict__ ctx) {
  __shared__ alignas(16) u16 Qs[64 * 64];
  __shared__ alignas(16) u16 Ks[2][64 * 64];
  __shared__ alignas(16) u16 Vs[2][64 * 64];
  __shared__ alignas(16) u16 Ps[4][16 * 72];
  int tid = threadIdx.x;
  int wave = tid >> 6, lane = tid & 63;
  int quad = lane >> 4, ln = lane & 15;
  int p2 = blockIdx.x;
  int bh, qt;
  if (p2 < 256) { bh = p2 & 63; qt = 7 - (p2 >> 6); }
  else          { int q2 = p2 - 256; bh = q2 & 63; qt = q2 >> 6; }
  int b = bh >> 3, h = bh & 7;
  int q0 = qt * 64;
  int kbe = qt;

  const u16* qb_ = q + ((size_t)(b * 512 + q0)) * 512 + h * 64;
  const u16* kb_ = k + ((size_t)(b * 512)) * 512 + h * 64;
  const u16* vb_ = vt + ((size_t)bh * 64) * 512;

  stage64(qb_, Qs, wave, lane);
  stage64(kb_, Ks[0], wave, lane);
  stage64(vb_, Vs[0], wave, lane);

  float m_r[4], l_r[4];
  f32x4 o[4];
  #pragma unroll
  for (int r = 0; r < 4; r++) { m_r[r] = -3.40282347e38f; l_r[r] = 0.f; }
  #pragma unroll
  for (int nt = 0; nt < 4; nt++) o[nt] = (f32x4){0.f, 0.f, 0.f, 0.f};

  int qrow = q0 + wave * 16 + quad * 4;

  float c_skv[4], c_bias[4][4];
  #pragma unroll
  for (int nt = 0; nt < 4; nt++) {
    int t = nt * 16 + ln;
    c_skv[nt] = summed[bh * 512 + t];
    const float* bp2 = bias_mat + ((size_t)(b * 512 + qrow)) * 512 + t;
    #pragma unroll
    for (int r = 0; r < 4; r++) c_bias[nt][r] = bp2[(size_t)r * 512];
  }

  int cur = 0;
  for (int kb = 0; kb <= kbe; kb++) {
    __syncthreads();

    float n_skv[4], n_bias[4][4];
    if (kb < kbe) {
      stage64(kb_ + (size_t)(kb + 1) * 64 * 512, Ks[cur ^ 1], wave, lane);
      stage64(vb_ + (kb + 1) * 64, Vs[cur ^ 1], wave, lane);
      #pragma unroll
      for (int nt = 0; nt < 4; nt++) {
        int t = (kb + 1) * 64 + nt * 16 + ln;
        n_skv[nt] = summed[bh * 512 + t];
        const float* bp2 = bias_mat + ((size_t)(b * 512 + qrow)) * 512 + t;
        #pragma unroll
        for (int r = 0; r < 4; r++) n_bias[nt][r] = bp2[(size_t)r * 512];
      }
    }

    bf16x8 aq0 = *(bf16x8*)&Qs[swz(wave * 16 + ln, quad)];
    bf16x8 aq1 = *(bf16x8*)&Qs[swz(wave * 16 + ln, 4 + quad)];
    f32x4 s[4];
    #pragma unroll
    for (int nt = 0; nt < 4; nt++) {
      bf16x8 b0 = *(bf16x8*)&Ks[cur][swz(nt * 16 + ln, quad)];
      bf16x8 b1 = *(bf16x8*)&Ks[cur][swz(nt * 16 + ln, 4 + quad)];
      s[nt] = (f32x4){0.f, 0.f, 0.f, 0.f};
      s[nt] = __builtin_amdgcn_mfma_f32_16x16x32_bf16(aq0, b0, s[nt], 0, 0, 0);
      s[nt] = __builtin_amdgcn_mfma_f32_16x16x32_bf16(aq1, b1, s[nt], 0, 0, 0);
    }

    #pragma unroll
    for (int nt = 0; nt < 4; nt++) {
      int t = kb * 64 + nt * 16 + ln;
      #pragma unroll
      for (int r = 0; r < 4; r++) {
        float val = s[nt][r] + c_bias[nt][r] * c_skv[nt];
        s[nt][r] = (t <= qrow + r) ? val : -3.40282347e38f;
      }
    }

    float alpha[4];
    #pragma unroll
    for (int r = 0; r < 4; r++) {
      float tm = fmaxf(fmaxf(s[0][r], s[1][r]), fmaxf(s[2][r], s[3][r]));
      #pragma unroll
      for (int off = 8; off; off >>= 1) tm = fmaxf(tm, __shfl_xor(tm, off));
      float mn = fmaxf(m_r[r], tm);
      alpha[r] = __expf(m_r[r] - mn);
      m_r[r] = mn;
      float rs = 0.f;
      #pragma unroll
      for (int nt = 0; nt < 4; nt++) {
        float pp = __expf(s[nt][r] - mn);
        s[nt][r] = pp;
        rs += pp;
      }
      #pragma unroll
      for (int off = 8; off; off >>= 1) rs += __shfl_xor(rs, off);
      l_r[r] = l_r[r] * alpha[r] + rs;
    }

    #pragma unroll
    for (int nt = 0; nt < 4; nt++)
      #pragma unroll
      for (int r = 0; r < 4; r++)
        Ps[wave][(quad * 4 + r) * 72 + nt * 16 + ln] = f2b(s[nt][r]);
    #pragma unroll
    for (int nt = 0; nt < 4; nt++)
      #pragma unroll
      for (int r = 0; r < 4; r++)
        o[nt][r] *= alpha[r];

    bf16x8 ap0 = *(bf16x8*)&Ps[wave][ln * 72 + quad * 8];
    bf16x8 ap1 = *(bf16x8*)&Ps[wave][ln * 72 + 32 + quad * 8];
    #pragma unroll
    for (int nt = 0; nt < 4; nt++) {
      bf16x8 b0 = *(bf16x8*)&Vs[cur][swz(nt * 16 + ln, quad)];
      bf16x8 b1 = *(bf16x8*)&Vs[cur][swz(nt * 16 + ln, 4 + quad)];
      o[nt] = __builtin_amdgcn_mfma_f32_16x16x32_bf16(ap0, b0, o[nt], 0, 0, 0);
      o[nt] = __builtin_amdgcn_mfma_f32_16x16x32_bf16(ap1, b1, o[nt], 0, 0, 0);
    }

    if (kb < kbe) {
      #pragma unroll
      for (int nt = 0; nt < 4; nt++) {
        c_skv[nt] = n_skv[nt];
        #pragma unroll
        for (int r = 0; r < 4; r++) c_bias[nt][r] = n_bias[nt][r];
      }
    }
    cur ^= 1;
  }

  #pragma unroll
  for (int r = 0; r < 4; r++) {
    float inv = 1.f / l_r[r];
    int qr2 = qrow + r;
    u16* dst = ctx + ((size_t)(b * 512 + qr2)) * 512 + h * 64;
    #pragma unroll
    for (int nt = 0; nt < 4; nt++)
      dst[nt * 16 + ln] = f2b(o[nt][r] * inv);
  }
}

// ---------- out GEMM: 64x64 tile; grid (64,8)=512 ----------
__global__ __launch_bounds__(256) void out_gemm(const u16* __restrict__ A,
                                                const u16* __restrict__ BT,
                                                float* __restrict__ C) {
  __shared__ alignas(16) u16 As[2][64 * 64];
  __shared__ alignas(16) u16 Bs[2][64 * 64];
  int tid = threadIdx.x;
  int lane = tid & 63, wave = tid >> 6;
  int quad = lane >> 4, ln = lane & 15;
  int wr = wave >> 1, wc = wave & 1;
  int row0 = blockIdx.x * 64;
  int col0 = blockIdx.y * 64;
  const u16* Ab = A + (size_t)row0 * 512;
  const u16* Bb = BT + (size_t)col0 * 512;

  f32x4 acc[2][2];
  #pragma unroll
  for (int i = 0; i < 2; i++)
    #pragma unroll
    for (int j = 0; j < 2; j++) acc[i][j] = (f32x4){0.f, 0.f, 0.f, 0.f};

  stage64(Ab, As[0], wave, lane);
  stage64(Bb, Bs[0], wave, lane);

  int cur = 0;
  for (int k0 = 0; k0 < 512; k0 += 64) {
    __syncthreads();
    if (k0 < 448) {
      stage64(Ab + k0 + 64, As[cur ^ 1], wave, lane);
      stage64(Bb + k0 + 64, Bs[cur ^ 1], wave, lane);
    }
    #pragma unroll
    for (int s = 0; s < 2; s++) {
      bf16x8 af[2], bfv[2];
      #pragma unroll
      for (int i = 0; i < 2; i++)
        af[i] = *(bf16x8*)&As[cur][swz(wr * 32 + i * 16 + ln, s * 4 + quad)];
      #pragma unroll
      for (int j = 0; j < 2; j++)
        bfv[j] = *(bf16x8*)&Bs[cur][swz(wc * 32 + j * 16 + ln, s * 4 + quad)];
      #pragma unroll
      for (int i = 0; i < 2; i++)
        #pragma unroll
        for (int j = 0; j < 2; j++)
          acc[i][j] = __builtin_amdgcn_mfma_f32_16x16x32_bf16(af[i], bfv[j], acc[i][j], 0, 0, 0);
    }
    cur ^= 1;
  }
  #pragma unroll
  for (int i = 0; i < 2; i++)
    #pragma unroll
    for (int j = 0; j < 2; j++) {
      int mb = row0 + wr * 32 + i * 16 + quad * 4;
      int n = col0 + wc * 32 + j * 16 + ln;
      #pragma unroll
      for (int r = 0; r < 4; r++)
        C[(size_t)(mb + r) * 512 + n] = acc[i][j][r];
    }
}

extern "C" void kernel_launch(void* const* d_in, const int* in_sizes, int n_in,
                              void* d_out, int out_size, void* d_ws, size_t ws_size,
                              hipStream_t stream) {
  const float* states     = (const float*)d_in[0];
  const float* key_states = (const float*)d_in[1];
  const int*   ab         = (const int*)d_in[3];
  const float* Wq         = (const float*)d_in[4];
  const float* Wk         = (const float*)d_in[5];
  const float* Wv         = (const float*)d_in[6];
  const float* Wo         = (const float*)d_in[7];
  const float* be         = (const float*)d_in[8];
  const float* bsc        = (const float*)d_in[9];
  float* out = (float*)d_out;

  char* ws = (char*)d_ws;
  const size_t MB = 1024 * 1024;
  // Compacted layout (~30 MB unique): ctxb ALIASES sb (sb dead after qkv).
  u16* wbase    = (u16*)(ws);                 // 2 MB: wqT|wkT|wvT|woT
  u16* wot      = (u16*)(ws + 1536 * 1024);
  u16* sb       = (u16*)(ws + 2 * MB);        // 4 MB bf16 states
  u16* ctxb     = sb;                         // reuse (attn writes after qkv reads)
  u16* kbin     = (u16*)(ws + 6 * MB);        // 4 MB bf16 key_states
  u16* qb       = (u16*)(ws + 10 * MB);       // 4 MB
  u16* kbo      = (u16*)(ws + 14 * MB);       // 4 MB
  u16* vtb      = (u16*)(ws + 18 * MB);       // 4 MB (b,h,a,t)
  float* bias_m = (float*)(ws + 22 * MB);     // 8 MB
  float* summed = (float*)(ws + 30 * MB);     // 128 KB

  int n_edges = in_sizes[3] / 4;

  prologue<<<dim3(5120), 256, 0, stream>>>(
      states, key_states, Wq, Wk, Wv, Wo, sb, kbin, wbase, bias_m);
  qkv_gemm<<<dim3(64, 12), 256, 0, stream>>>(
      sb, kbin, wbase, ab, be, bsc, bias_m, qb, kbo, vtb, summed, n_edges);
  attn_mfma<<<dim3(512), 256, 0, stream>>>(qb, kbo, vtb, bias_m, summed, ctxb);
  out_gemm<<<dim3(64, 8), 256, 0, stream>>>(ctxb, wot, out);
}